// Round 4
// baseline (430.606 us; speedup 1.0000x reference)
//
#include <hip/hip_runtime.h>

typedef short short8  __attribute__((ext_vector_type(8)));
typedef short shortx4 __attribute__((ext_vector_type(4)));
typedef float floatx4 __attribute__((ext_vector_type(4)));
typedef unsigned short u16;

static __device__ __forceinline__ float bits2f(u16 s) {
    return __builtin_bit_cast(float, (unsigned)s << 16);
}
static __device__ __forceinline__ u16 f2bits(float f) {
    return __builtin_bit_cast(u16, (__bf16)f);   // RNE
}

#define SS 16

// ---- weight prepack: wt[tap][ko][ci] bf16 + 64-entry zero bias ------------
__global__ void prep_kernel(const float* W0, const float* R0, const float* W1,
                            u16* wt0, u16* wtR, u16* wt1, float* zb) {
    const int i = blockIdx.x * 256 + threadIdx.x;
    if (i < 36864) {
        const int t = i / 4096, r = i % 4096, ko = r >> 5, ci = r & 31;
        wt0[i] = f2bits(W0[(ko * 32 + ci) * 9 + t]);
    } else if (i < 36864 + 18432) {
        const int j = i - 36864;
        const int t = j / 2048, r = j % 2048, ko = r >> 5, ci = r & 31;
        wtR[j] = f2bits(R0[(ko * 32 + ci) * 9 + t]);
    } else if (i < 36864 + 18432 + 73728) {
        const int j = i - 36864 - 18432;
        const int t = j / 8192, r = j % 8192, ko = r >> 6, ci = r & 63;
        wt1[j] = f2bits(W1[(ko * 64 + ci) * 9 + t]);
    } else if (i < 36864 + 18432 + 73728 + 64) {
        zb[i - 129024] = 0.0f;
    }
}

// ---- x (64,32,64,64) f32 NCHW -> xT (64,64,64,32) bf16 NHWC ---------------
__global__ void transpose_kernel(const float* __restrict__ x, u16* __restrict__ xT) {
    const int img = blockIdx.x >> 6, h = blockIdx.x & 63;
    const int gq = threadIdx.x & 3, w = threadIdx.x >> 2;
    short8 o;
#pragma unroll
    for (int k = 0; k < 8; ++k)
        o[k] = (short)f2bits(x[((size_t)img * 32 + gq * 8 + k) * 4096 + h * 64 + w]);
    ((short8*)xT)[((size_t)(img * 64 + h) * 64 + w) * 4 + gq] = o;
}

// ---- MFMA implicit-GEMM 3x3 conv, pad 1, NHWC -----------------------------
// X (64,64,64,CI) bf16 NHWC; wt [9][KOT][CI] bf16; bias (KOT) f32;
// Y (64,64,64,KOT) bf16 NHWC. Block 256 = 4 waves; one image x 4-row strip
// x 64 output channels (ko-split across blockIdx.y when KOT=128).
// KPW=1: per-wave state = 64 AGPR acc + 36 VGPR weights -> ~170-reg budget,
// 3 blocks/CU (launch_bounds(256,3); round-0's KPW=2 needed 256 regs -> 2
// blocks/CU in lockstep = every staging sync stalled the whole SIMD).
// grid(16 strips, KOT/64, 64 img). Epilogue: LDS transpose -> nt stores.
template<int CI, int KOT>
__global__ __launch_bounds__(256, 3)
void conv3x3_mfma_kernel(const u16* __restrict__ X, const u16* __restrict__ wt,
                         const float* __restrict__ bias, u16* __restrict__ Y) {
    constexpr int CG  = CI / 8;            // 16B ci-granules per pixel (in)
    constexpr int CGS = (CG == 4) ? 2 : 3; // log2(CG)
    constexpr int NGB = 8;                 // 16B ko-granules per pixel (block out)
    constexpr int NGT = KOT / 8;           // 16B ko-granules per pixel (Y stride)
    constexpr int PXS = NGB + 1;           // padded pixel stride (granules)
    constexpr int SG  = 6 * 66 * CG;       // staging granules
    constexpr int EPG = 128 * PXS;         // epilogue granules (2 rows x 64 px)
    constexpr int LSZ = (SG > EPG) ? SG : EPG;
    __shared__ short8 lds[LSZ];

    const int l   = threadIdx.x & 63;
    const int wv  = threadIdx.x >> 6;
    const int c16 = l & 15;
    const int q16 = l >> 4;
    const int h0  = blockIdx.x * 4;
    const int koh = blockIdx.y;
    const int n   = blockIdx.z;

    // zero staging LDS (borders + out-of-range rows stay zero)
    {
        const short8 z = {0, 0, 0, 0, 0, 0, 0, 0};
        for (int i = threadIdx.x; i < SG; i += 256) lds[i] = z;
    }
    __syncthreads();

    // stage rows h0-1..h0+4: contiguous 16B granule loads + swizzled ds_write
    const short8* Xg = (const short8*)X;
    for (int task = wv; task < 6 * CG; task += 4) {
        const int r     = task >> CGS;
        const int chunk = task & (CG - 1);
        const int h     = h0 + r - 1;
        if (h >= 0 && h < 64) {
            const int colrel = chunk * (64 / CG) + (l >> CGS);
            const int q      = l & (CG - 1);
            const int col    = 1 + colrel;
            const short8 v = Xg[((size_t)(n * 64 + h) * 64 + colrel) * CG + q];
            lds[(r * 66 + col) * CG + ((q + col) & (CG - 1))] = v;
        }
    }
    __syncthreads();

    // this wave's 16-ko group (global index within KOT)
    const int kog = koh * 4 + wv;

    floatx4 acc[16];
    {
        const floatx4 init = *(const floatx4*)(bias + kog * 16 + q16 * 4);
#pragma unroll
        for (int p = 0; p < 16; ++p) acc[p] = init;
    }

    const short8* wtv = (const short8*)wt;
#pragma unroll
    for (int ch = 0; ch < CI / 32; ++ch) {
        short8 af[9];
#pragma unroll
        for (int t = 0; t < 9; ++t)
            af[t] = wtv[(size_t)(t * KOT + kog * 16 + c16) * CG + ch * 4 + q16];
#pragma unroll
        for (int t = 0; t < 9; ++t) {
            const int dy = t / 3, dx = t - dy * 3;
#pragma unroll
            for (int p = 0; p < 16; ++p) {
                const int row = (p >> 2) + dy;
                const int col = (p & 3) * 16 + dx + c16;
                const int q   = ch * 4 + q16;
                const short8 bf = lds[(row * 66 + col) * CG + ((q + col) & (CG - 1))];
                acc[p] = __builtin_amdgcn_mfma_f32_16x16x32_bf16(af[t], bf, acc[p], 0, 0, 0);
            }
        }
    }

    // epilogue: 2 rows at a time through LDS, then coalesced nt stores
    // (block writes its 64-ko half: 128B bursts per pixel)
    shortx4* lq = (shortx4*)lds;
#pragma unroll
    for (int rp = 0; rp < 2; ++rp) {
        __syncthreads();   // staging (rp=0) / previous readback (rp=1) done
        {
            const int qoff = wv * 4 + q16;   // shortx4 slot within 128B
#pragma unroll
            for (int pp = 0; pp < 8; ++pp) {
                const int p   = rp * 8 + pp;
                const int pxl = ((p >> 2) & 1) * 64 + (p & 3) * 16 + c16;
                shortx4 ov;
#pragma unroll
                for (int r = 0; r < 4; ++r) ov[r] = (short)f2bits(acc[p][r]);
                lq[pxl * (2 * PXS) + qoff] = ov;
            }
        }
        __syncthreads();
#pragma unroll
        for (int i = 0; i < NGB / 2; ++i) {
            const int L  = i * 256 + (int)threadIdx.x;
            const int px = L / NGB, g = L % NGB;
            const int h  = h0 + 2 * rp + (px >> 6);
            const int w  = px & 63;
            const short8 v = lds[px * PXS + g];
            __builtin_nontemporal_store(
                v, (short8*)Y + ((size_t)(n * 64 + h) * 64 + w) * NGT + koh * NGB + g);
        }
    }
}

// ---- minGRU scan + residual, full batch, NHWC -----------------------------
// Yg (64,4096,128) bf16 NHWC: gate ch [0,64), hidden [64,128). R (64,4096,64).
// FINAL=0: out = x1 bf16 NHWC. FINAL=1: out = f32 NCHW via LDS transpose.
// hlast (B,64,HW) f32 via LDS transpose. Block: 16 hw x 16 cg.
template<bool FINAL>
__global__ void gru_kernel(const u16* __restrict__ Yg, const u16* __restrict__ R,
                           void* __restrict__ outp, float* __restrict__ hlast) {
    __shared__ float lds_t[16 * 68];
    const int cg  = threadIdx.x & 15;
    const int hwl = threadIdx.x >> 4;
    const int b   = blockIdx.x >> 8;
    const int hwh = blockIdx.x & 255;
    const int hw  = hwh * 16 + hwl;
    const shortx4* Yv = (const shortx4*)Yg;
    const shortx4* Rv = (const shortx4*)R;
    float h[4] = {0.5f, 0.5f, 0.5f, 0.5f};
#pragma unroll
    for (int s = 0; s < SS; ++s) {
        const size_t px = (size_t)(b * 16 + s) * 4096 + hw;
        const shortx4 g4 = Yv[px * 32 + cg];
        const shortx4 d4 = Yv[px * 32 + 16 + cg];
        const shortx4 r4 = Rv[px * 16 + cg];
        float o[4];
#pragma unroll
        for (int j = 0; j < 4; ++j) {
            const float g   = bits2f((u16)g4[j]);
            const float hid = bits2f((u16)d4[j]);
            const float z   = 1.0f / (1.0f + __expf(-g));
            const float gg  = (hid >= 0.0f) ? (hid + 0.5f) : (1.0f / (1.0f + __expf(-hid)));
            h[j] = h[j] + z * (gg - h[j]);             // (1-z)*h + z*gg
            o[j] = h[j] + bits2f((u16)r4[j]);
        }
        if (!FINAL) {
            shortx4 ov;
#pragma unroll
            for (int j = 0; j < 4; ++j) ov[j] = (short)f2bits(o[j]);
            ((shortx4*)outp)[px * 16 + cg] = ov;
        } else {
            floatx4 o4;
#pragma unroll
            for (int j = 0; j < 4; ++j) o4[j] = o[j];
            *(floatx4*)(&lds_t[hwl * 68 + cg * 4]) = o4;
            __syncthreads();
            const int c2 = threadIdx.x >> 2, h4 = threadIdx.x & 3;
            floatx4 v;
#pragma unroll
            for (int k = 0; k < 4; ++k) v[k] = lds_t[(h4 * 4 + k) * 68 + c2];
            *(floatx4*)((float*)outp +
                        ((size_t)(b * 16 + s) * 64 + c2) * 4096 + hwh * 16 + h4 * 4) = v;
            __syncthreads();
        }
    }
    // hlast: per-thread NHWC regs -> NCHW f32 via LDS transpose (64B segments)
    {
        floatx4 h4v;
#pragma unroll
        for (int j = 0; j < 4; ++j) h4v[j] = h[j];
        if (!FINAL) __syncthreads();   // FINAL path already synced at loop end
        *(floatx4*)(&lds_t[hwl * 68 + cg * 4]) = h4v;
        __syncthreads();
        const int c2 = threadIdx.x >> 2, h4 = threadIdx.x & 3;
        floatx4 v;
#pragma unroll
        for (int k = 0; k < 4; ++k) v[k] = lds_t[(h4 * 4 + k) * 68 + c2];
        *(floatx4*)(hlast + ((size_t)b * 64 + c2) * 4096 + hwh * 16 + h4 * 4) = v;
    }
}

extern "C" void kernel_launch(void* const* d_in, const int* in_sizes, int n_in,
                              void* d_out, int out_size, void* d_ws, size_t ws_size,
                              hipStream_t stream) {
    const float* x  = (const float*)d_in[0];   // (4,16,32,64,64)
    const float* W0 = (const float*)d_in[1];   // (128,32,3,3)
    const float* b0 = (const float*)d_in[2];   // (128,)
    const float* R0 = (const float*)d_in[3];   // (64,32,3,3)
    const float* W1 = (const float*)d_in[4];   // (128,64,3,3)
    const float* b1 = (const float*)d_in[5];   // (128,)

    float* out = (float*)d_out;                 // (4,16,64,64,64) NCHW f32
    float* h0o = out + (size_t)16777216;
    float* h1o = h0o + (size_t)1048576;

    char* ws = (char*)d_ws;
    u16*   wt0 = (u16*)ws;                              // 73,728 B
    u16*   wtR = (u16*)(ws + 73728);                    // 36,864 B
    u16*   wt1 = (u16*)(ws + 110592);                   // 147,456 B
    float* zb  = (float*)(ws + 258048);                 // 256 B
    u16*   xT  = (u16*)(ws + (size_t)(1  << 20));       // 16 MiB (NHWC bf16 input)
    u16*   x1  = xT;                                    // 32 MiB; overwrites xT after convs
    u16*   y0  = (u16*)(ws + (size_t)(33 << 20));       // 64 MiB (NHWC 128ch)
    u16*   r0  = (u16*)(ws + (size_t)(97 << 20));       // 32 MiB (NHWC 64ch) -> ends 129 MiB

    prep_kernel<<<505, 256, 0, stream>>>(W0, R0, W1, wt0, wtR, wt1, zb);
    transpose_kernel<<<4096, 256, 0, stream>>>(x, xT);

    // Layer 0 (full batch): gate/hidden conv + residual conv + scan -> x1
    conv3x3_mfma_kernel<32, 128><<<dim3(16, 2, 64), 256, 0, stream>>>(xT, wt0, b0, y0);
    conv3x3_mfma_kernel<32, 64 ><<<dim3(16, 1, 64), 256, 0, stream>>>(xT, wtR, zb, r0);
    gru_kernel<false><<<1024, 256, 0, stream>>>(y0, r0, x1, h0o);

    // Layer 1: conv from x1 -> y0 (reuse), scan with identity residual -> out
    conv3x3_mfma_kernel<64, 128><<<dim3(16, 2, 64), 256, 0, stream>>>(x1, wt1, b1, y0);
    gru_kernel<true ><<<1024, 256, 0, stream>>>(y0, x1, out, h1o);
}

// Round 6
// 236.433 us; speedup vs baseline: 1.8213x; 1.8213x over previous
//
#include <hip/hip_runtime.h>

typedef short short8  __attribute__((ext_vector_type(8)));
typedef short shortx4 __attribute__((ext_vector_type(4)));
typedef float floatx4 __attribute__((ext_vector_type(4)));
typedef unsigned short u16;

static __device__ __forceinline__ float bits2f(u16 s) {
    return __builtin_bit_cast(float, (unsigned)s << 16);
}
static __device__ __forceinline__ u16 f2bits(float f) {
    return __builtin_bit_cast(u16, (__bf16)f);   // RNE
}

#define SS 16

// ---- weight prepack: wt[tap][ko][ci] bf16 + 64-entry zero bias ------------
__global__ void prep_kernel(const float* W0, const float* R0, const float* W1,
                            u16* wt0, u16* wtR, u16* wt1, float* zb) {
    const int i = blockIdx.x * 256 + threadIdx.x;
    if (i < 36864) {
        const int t = i / 4096, r = i % 4096, ko = r >> 5, ci = r & 31;
        wt0[i] = f2bits(W0[(ko * 32 + ci) * 9 + t]);
    } else if (i < 36864 + 18432) {
        const int j = i - 36864;
        const int t = j / 2048, r = j % 2048, ko = r >> 5, ci = r & 31;
        wtR[j] = f2bits(R0[(ko * 32 + ci) * 9 + t]);
    } else if (i < 36864 + 18432 + 73728) {
        const int j = i - 36864 - 18432;
        const int t = j / 8192, r = j % 8192, ko = r >> 6, ci = r & 63;
        wt1[j] = f2bits(W1[(ko * 64 + ci) * 9 + t]);
    } else if (i < 36864 + 18432 + 73728 + 64) {
        zb[i - 129024] = 0.0f;
    }
}

// ---- x (64,32,64,64) f32 NCHW -> xT (64,64,64,32) bf16 NHWC ---------------
__global__ void transpose_kernel(const float* __restrict__ x, u16* __restrict__ xT) {
    const int img = blockIdx.x >> 6, h = blockIdx.x & 63;
    const int gq = threadIdx.x & 3, w = threadIdx.x >> 2;
    short8 o;
#pragma unroll
    for (int k = 0; k < 8; ++k)
        o[k] = (short)f2bits(x[((size_t)img * 32 + gq * 8 + k) * 4096 + h * 64 + w]);
    ((short8*)xT)[((size_t)(img * 64 + h) * 64 + w) * 4 + gq] = o;
}

// ---- MFMA implicit-GEMM 3x3 conv, pad 1, NHWC (layer-0 only now) ----------
// Exact round-0 machinery (verified 319.5us). X (64,64,64,CI) bf16 NHWC;
// wt [9][KO][CI] bf16; bias (KO) f32; Y (64,64,64,KO) bf16 NHWC.
// Block 256 = 4 waves; one image x 4-row strip. grid(16 strips, 64 img).
template<int CI, int KO>
__global__ __launch_bounds__(256, 2)
void conv3x3_mfma_kernel(const u16* __restrict__ X, const u16* __restrict__ wt,
                         const float* __restrict__ bias, u16* __restrict__ Y) {
    constexpr int CG  = CI / 8;            // 16B ci-granules per pixel
    constexpr int CGS = (CG == 4) ? 2 : 3; // log2(CG)
    constexpr int KPW = KO / 64;
    constexpr int NG  = KO / 8;            // 16B ko-granules per pixel (out)
    constexpr int PXS = NG + 1;            // padded pixel stride (granules)
    constexpr int SG  = 6 * 66 * CG;       // staging granules
    constexpr int EPG = 128 * PXS;         // epilogue granules (2 rows x 64 px)
    constexpr int LSZ = (SG > EPG) ? SG : EPG;
    __shared__ short8 lds[LSZ];

    const int l   = threadIdx.x & 63;
    const int wv  = threadIdx.x >> 6;
    const int c16 = l & 15;
    const int q16 = l >> 4;
    const int h0  = blockIdx.x * 4;
    const int n   = blockIdx.y;

    // zero staging LDS (borders + out-of-range rows stay zero)
    {
        const short8 z = {0, 0, 0, 0, 0, 0, 0, 0};
        for (int i = threadIdx.x; i < SG; i += 256) lds[i] = z;
    }
    __syncthreads();

    // stage rows h0-1..h0+4: contiguous 16B granule loads + swizzled ds_write
    const short8* Xg = (const short8*)X;
    for (int task = wv; task < 6 * CG; task += 4) {
        const int r     = task >> CGS;
        const int chunk = task & (CG - 1);
        const int h     = h0 + r - 1;
        if (h >= 0 && h < 64) {
            const int colrel = chunk * (64 / CG) + (l >> CGS);
            const int q      = l & (CG - 1);
            const int col    = 1 + colrel;
            const short8 v = Xg[((size_t)(n * 64 + h) * 64 + colrel) * CG + q];
            lds[(r * 66 + col) * CG + ((q + col) & (CG - 1))] = v;
        }
    }
    __syncthreads();

    const int kogb = wv * KPW;
    floatx4 acc[KPW][16];
#pragma unroll
    for (int kpw = 0; kpw < KPW; ++kpw) {
        const floatx4 init = *(const floatx4*)(bias + (kogb + kpw) * 16 + q16 * 4);
#pragma unroll
        for (int p = 0; p < 16; ++p) acc[kpw][p] = init;
    }

    const short8* wtv = (const short8*)wt;
#pragma unroll
    for (int ch = 0; ch < CI / 32; ++ch) {
        short8 af[KPW][9];
#pragma unroll
        for (int t = 0; t < 9; ++t)
#pragma unroll
            for (int kpw = 0; kpw < KPW; ++kpw)
                af[kpw][t] = wtv[(size_t)(t * KO + (kogb + kpw) * 16 + c16) * CG
                                 + ch * 4 + q16];
#pragma unroll
        for (int t = 0; t < 9; ++t) {
            const int dy = t / 3, dx = t - dy * 3;
#pragma unroll
            for (int p = 0; p < 16; ++p) {
                const int row = (p >> 2) + dy;
                const int col = (p & 3) * 16 + dx + c16;
                const int q   = ch * 4 + q16;
                const short8 bf = lds[(row * 66 + col) * CG + ((q + col) & (CG - 1))];
#pragma unroll
                for (int kpw = 0; kpw < KPW; ++kpw)
                    acc[kpw][p] = __builtin_amdgcn_mfma_f32_16x16x32_bf16(
                        af[kpw][t], bf, acc[kpw][p], 0, 0, 0);
            }
        }
    }

    // epilogue: 2 rows at a time through LDS, then fully-coalesced nt stores
    shortx4* lq = (shortx4*)lds;
#pragma unroll
    for (int rp = 0; rp < 2; ++rp) {
        __syncthreads();   // staging (rp=0) / previous readback (rp=1) done
#pragma unroll
        for (int kpw = 0; kpw < KPW; ++kpw) {
            const int qoff = (kogb + kpw) * 4 + q16;
#pragma unroll
            for (int pp = 0; pp < 8; ++pp) {
                const int p   = rp * 8 + pp;
                const int pxl = ((p >> 2) & 1) * 64 + (p & 3) * 16 + c16;
                shortx4 ov;
#pragma unroll
                for (int r = 0; r < 4; ++r) ov[r] = (short)f2bits(acc[kpw][p][r]);
                lq[pxl * (2 * PXS) + qoff] = ov;
            }
        }
        __syncthreads();
#pragma unroll
        for (int i = 0; i < NG / 2; ++i) {
            const int L  = i * 256 + (int)threadIdx.x;
            const int px = L / NG, g = L % NG;
            const int h  = h0 + 2 * rp + (px >> 6);
            const int w  = px & 63;
            const short8 v = lds[px * PXS + g];
            __builtin_nontemporal_store(
                v, (short8*)Y + ((size_t)(n * 64 + h) * 64 + w) * NG + g);
        }
    }
}

// ---- fused layer 1: conv3x3(64->128) + minGRU scan + residual -------------
// X = x1 (64,64,64,64) bf16 NHWC. wt [9][128][64] bf16; bias (128) f32.
// out (4,16,64,64,64) f32 NCHW; hlast (4,64,64,64) f32 NCHW.
// Block = (b, 2-row strip, 32-col half): grid 4*32*2 = 256, 4 waves.
// Per timestep: stage 4 rows x 34 cols of x1[s] into LDS (register-prefetched
// during previous step's compute), implicit-GEMM conv, per-thread GRU update
// with persistent h in registers, residual from staged LDS, direct f32 store.
// Wave wv owns ko-tiles {wv (gate ch wv*16..), wv+4 (hidden = same+64)}:
// each thread's acc holds matched (gate,hidden) pairs for one pixel.
// Weights (36 granules = 144 VGPR) hoisted once per block across all 16 ts.
__global__ __launch_bounds__(256, 1)
void fused_layer1_kernel(const u16* __restrict__ X, const u16* __restrict__ wt,
                         const float* __restrict__ bias,
                         float* __restrict__ out, float* __restrict__ hlast) {
    __shared__ short8 lds[4 * 34 * 8];   // 17408 B

    const int tid = threadIdx.x;
    const int l   = tid & 63;
    const int wv  = tid >> 6;
    const int c16 = l & 15;
    const int q16 = l >> 4;

    const int bid = blockIdx.x;
    const int b   = bid >> 6;
    const int h0  = ((bid >> 1) & 31) * 2;
    const int w0  = (bid & 1) * 32;

    // ---- weights: all 36 granules hoisted (static across timesteps) ----
    const short8* wtv = (const short8*)wt;
    short8 af[2][9][2];
#pragma unroll
    for (int ch = 0; ch < 2; ++ch)
#pragma unroll
        for (int t = 0; t < 9; ++t)
#pragma unroll
            for (int g = 0; g < 2; ++g)
                af[ch][t][g] =
                    wtv[(size_t)(t * 128 + (wv + g * 4) * 16 + c16) * 8 + ch * 4 + q16];

    const floatx4 biasg = *(const floatx4*)(bias + wv * 16 + q16 * 4);
    const floatx4 biash = *(const floatx4*)(bias + 64 + wv * 16 + q16 * 4);

    // ---- staging geometry (static per thread): 1088 granules = 4r x 34c x 8q
    int ldsoff[5], goff[5];
    bool gval[5];
#pragma unroll
    for (int k = 0; k < 5; ++k) {
        const int idx = tid + k * 256;
        const int row = (idx >= 816) ? 3 : (idx >= 544) ? 2 : (idx >= 272) ? 1 : 0;
        const int rem = idx - row * 272;
        const int colrel = rem >> 3, q = rem & 7;
        const int hh = h0 - 1 + row;
        const int gc = w0 - 1 + colrel;
        ldsoff[k] = (row * 34 + colrel) * 8 + ((q + colrel) & 7);
        gval[k]   = (idx < 1088) && ((unsigned)hh < 64u) && ((unsigned)gc < 64u);
        goff[k]   = (hh * 64 + gc) * 8 + q;
    }
    const bool k4 = (tid < 64);   // k=4 slot exists only for idx<1088

    float hs[4][4];
#pragma unroll
    for (int m = 0; m < 4; ++m)
#pragma unroll
        for (int r = 0; r < 4; ++r) hs[m][r] = 0.5f;

    // out base for this thread: ch c=wv*16+q16*4, px (h0+(m>>1), w0+(m&1)*16+c16)
    float* op = out + ((size_t)(b * 16) * 64 + (wv * 16 + q16 * 4)) * 4096
                    + h0 * 64 + w0 + c16;

    const short8* Xg = (const short8*)X;
    const short8 z8 = {0, 0, 0, 0, 0, 0, 0, 0};

    // prologue: load s=0 into regs
    short8 v0, v1, v2, v3, v4;
    {
        const short8* base = Xg + (size_t)(b * 16) * 32768;
        v0 = gval[0] ? base[goff[0]] : z8;
        v1 = gval[1] ? base[goff[1]] : z8;
        v2 = gval[2] ? base[goff[2]] : z8;
        v3 = gval[3] ? base[goff[3]] : z8;
        v4 = gval[4] ? base[goff[4]] : z8;
    }

    for (int s = 0; s < SS; ++s) {
        // write staged tile (invalid slots carry zeros -> halo stays zero)
        lds[ldsoff[0]] = v0;
        lds[ldsoff[1]] = v1;
        lds[ldsoff[2]] = v2;
        lds[ldsoff[3]] = v3;
        if (k4) lds[ldsoff[4]] = v4;
        __syncthreads();

        // prefetch next timestep while computing this one
        if (s + 1 < SS) {
            const short8* base = Xg + (size_t)(b * 16 + s + 1) * 32768;
            v0 = gval[0] ? base[goff[0]] : z8;
            v1 = gval[1] ? base[goff[1]] : z8;
            v2 = gval[2] ? base[goff[2]] : z8;
            v3 = gval[3] ? base[goff[3]] : z8;
            v4 = gval[4] ? base[goff[4]] : z8;
        }

        // conv: acc[0]=gate tiles, acc[1]=hidden tiles, m = px-tile
        floatx4 acc[2][4];
#pragma unroll
        for (int m = 0; m < 4; ++m) { acc[0][m] = biasg; acc[1][m] = biash; }
#pragma unroll
        for (int ch = 0; ch < 2; ++ch)
#pragma unroll
            for (int t = 0; t < 9; ++t) {
                const int dy = t / 3, dx = t - dy * 3;
#pragma unroll
                for (int m = 0; m < 4; ++m) {
                    const int row = (m >> 1) + dy;
                    const int lc  = (m & 1) * 16 + c16 + dx;
                    const short8 bf =
                        lds[(row * 34 + lc) * 8 + ((ch * 4 + q16 + lc) & 7)];
                    acc[0][m] = __builtin_amdgcn_mfma_f32_16x16x32_bf16(
                        af[ch][t][0], bf, acc[0][m], 0, 0, 0);
                    acc[1][m] = __builtin_amdgcn_mfma_f32_16x16x32_bf16(
                        af[ch][t][1], bf, acc[1][m], 0, 0, 0);
                }
            }

        // GRU update + residual + direct NCHW f32 store
        float* ops = op + (size_t)s * 262144;   // 64*4096 floats per timestep
        const int qres = wv * 2 + (q16 >> 1);
#pragma unroll
        for (int m = 0; m < 4; ++m) {
            const int rowc = 1 + (m >> 1);
            const int lcc  = 1 + (m & 1) * 16 + c16;
            const shortx4 rr = *(const shortx4*)(
                (const short*)&lds[(rowc * 34 + lcc) * 8 + ((qres + lcc) & 7)]
                + (q16 & 1) * 4);
#pragma unroll
            for (int r = 0; r < 4; ++r) {
                const float g   = acc[0][m][r];
                const float hid = acc[1][m][r];
                const float zz  = 1.0f / (1.0f + __expf(-g));
                const float gg  = (hid >= 0.0f) ? (hid + 0.5f)
                                                : (1.0f / (1.0f + __expf(-hid)));
                hs[m][r] = hs[m][r] + zz * (gg - hs[m][r]);
                const float o = hs[m][r] + bits2f((u16)rr[r]);
                ops[(size_t)r * 4096 + (m >> 1) * 64 + (m & 1) * 16] = o;
            }
        }
        __syncthreads();   // all waves done reading lds before next ds_write
    }

    // hlast (4,64,64,64) f32 NCHW
    float* hp = hlast + ((size_t)(b * 64) + (wv * 16 + q16 * 4)) * 4096
                      + h0 * 64 + w0 + c16;
#pragma unroll
    for (int m = 0; m < 4; ++m)
#pragma unroll
        for (int r = 0; r < 4; ++r)
            hp[(size_t)r * 4096 + (m >> 1) * 64 + (m & 1) * 16] = hs[m][r];
}

// ---- minGRU scan + residual for layer 0, full batch, NHWC -----------------
// Yg (64,4096,128) bf16 NHWC: gate ch [0,64), hidden [64,128). R (64,4096,64).
// out = x1 bf16 NHWC. hlast (B,64,HW) f32 via LDS transpose.
__global__ void gru_kernel(const u16* __restrict__ Yg, const u16* __restrict__ R,
                           void* __restrict__ outp, float* __restrict__ hlast) {
    __shared__ float lds_t[16 * 68];
    const int cg  = threadIdx.x & 15;
    const int hwl = threadIdx.x >> 4;
    const int b   = blockIdx.x >> 8;
    const int hwh = blockIdx.x & 255;
    const int hw  = hwh * 16 + hwl;
    const shortx4* Yv = (const shortx4*)Yg;
    const shortx4* Rv = (const shortx4*)R;
    float h[4] = {0.5f, 0.5f, 0.5f, 0.5f};
#pragma unroll
    for (int s = 0; s < SS; ++s) {
        const size_t px = (size_t)(b * 16 + s) * 4096 + hw;
        const shortx4 g4 = Yv[px * 32 + cg];
        const shortx4 d4 = Yv[px * 32 + 16 + cg];
        const shortx4 r4 = Rv[px * 16 + cg];
        float o[4];
#pragma unroll
        for (int j = 0; j < 4; ++j) {
            const float g   = bits2f((u16)g4[j]);
            const float hid = bits2f((u16)d4[j]);
            const float z   = 1.0f / (1.0f + __expf(-g));
            const float gg  = (hid >= 0.0f) ? (hid + 0.5f) : (1.0f / (1.0f + __expf(-hid)));
            h[j] = h[j] + z * (gg - h[j]);             // (1-z)*h + z*gg
            o[j] = h[j] + bits2f((u16)r4[j]);
        }
        shortx4 ov;
#pragma unroll
        for (int j = 0; j < 4; ++j) ov[j] = (short)f2bits(o[j]);
        ((shortx4*)outp)[px * 16 + cg] = ov;
    }
    // hlast: per-thread NHWC regs -> NCHW f32 via LDS transpose (64B segments)
    {
        floatx4 h4v;
#pragma unroll
        for (int j = 0; j < 4; ++j) h4v[j] = h[j];
        __syncthreads();
        *(floatx4*)(&lds_t[hwl * 68 + cg * 4]) = h4v;
        __syncthreads();
        const int c2 = threadIdx.x >> 2, h4 = threadIdx.x & 3;
        floatx4 v;
#pragma unroll
        for (int k = 0; k < 4; ++k) v[k] = lds_t[(h4 * 4 + k) * 68 + c2];
        *(floatx4*)(hlast + ((size_t)b * 64 + c2) * 4096 + hwh * 16 + h4 * 4) = v;
    }
}

extern "C" void kernel_launch(void* const* d_in, const int* in_sizes, int n_in,
                              void* d_out, int out_size, void* d_ws, size_t ws_size,
                              hipStream_t stream) {
    const float* x  = (const float*)d_in[0];   // (4,16,32,64,64)
    const float* W0 = (const float*)d_in[1];   // (128,32,3,3)
    const float* b0 = (const float*)d_in[2];   // (128,)
    const float* R0 = (const float*)d_in[3];   // (64,32,3,3)
    const float* W1 = (const float*)d_in[4];   // (128,64,3,3)
    const float* b1 = (const float*)d_in[5];   // (128,)

    float* out = (float*)d_out;                 // (4,16,64,64,64) NCHW f32
    float* h0o = out + (size_t)16777216;
    float* h1o = h0o + (size_t)1048576;

    char* ws = (char*)d_ws;
    u16*   wt0 = (u16*)ws;                              // 73,728 B
    u16*   wtR = (u16*)(ws + 73728);                    // 36,864 B
    u16*   wt1 = (u16*)(ws + 110592);                   // 147,456 B
    float* zb  = (float*)(ws + 258048);                 // 256 B
    u16*   xT  = (u16*)(ws + (size_t)(1  << 20));       // 16 MiB (NHWC bf16 input)
    u16*   x1  = xT;                                    // 32 MiB; overwrites xT after convs
    u16*   y0  = (u16*)(ws + (size_t)(33 << 20));       // 64 MiB (NHWC 128ch)
    u16*   r0  = (u16*)(ws + (size_t)(97 << 20));       // 32 MiB (NHWC 64ch) -> ends 129 MiB

    prep_kernel<<<505, 256, 0, stream>>>(W0, R0, W1, wt0, wtR, wt1, zb);
    transpose_kernel<<<4096, 256, 0, stream>>>(x, xT);

    // Layer 0 (full batch): gate/hidden conv + residual conv + scan -> x1
    conv3x3_mfma_kernel<32, 128><<<dim3(16, 64), 256, 0, stream>>>(xT, wt0, b0, y0);
    conv3x3_mfma_kernel<32, 64 ><<<dim3(16, 64), 256, 0, stream>>>(xT, wtR, zb, r0);
    gru_kernel<<<1024, 256, 0, stream>>>(y0, r0, x1, h0o);

    // Layer 1: fused conv(64->128) + GRU scan + residual -> out, h1o
    fused_layer1_kernel<<<256, 256, 0, stream>>>(x1, wt1, b1, out, h1o);
}

// Round 7
// 206.417 us; speedup vs baseline: 2.0861x; 1.1454x over previous
//
#include <hip/hip_runtime.h>

typedef short short8  __attribute__((ext_vector_type(8)));
typedef short shortx4 __attribute__((ext_vector_type(4)));
typedef float floatx4 __attribute__((ext_vector_type(4)));
typedef unsigned short u16;

static __device__ __forceinline__ float bits2f(u16 s) {
    return __builtin_bit_cast(float, (unsigned)s << 16);
}
static __device__ __forceinline__ u16 f2bits(float f) {
    return __builtin_bit_cast(u16, (__bf16)f);   // RNE
}

#define SS 16

// ---- weight prepack ------------------------------------------------------
// wt0f [9][192][32] bf16 : ko<128 from W0 (gate 0-63, hidden 64-127),
//                          ko>=128 from R0 (residual). (r1-verified layout)
// wt1  [9][128][64] bf16
__global__ void prep_kernel(const float* W0, const float* R0, const float* W1,
                            u16* wt0f, u16* wt1) {
    const int i = blockIdx.x * 256 + threadIdx.x;
    if (i < 55296) {
        const int t = i / 6144, r = i % 6144, ko = r >> 5, ci = r & 31;
        wt0f[i] = f2bits(ko < 128 ? W0[(ko * 32 + ci) * 9 + t]
                                  : R0[((ko - 128) * 32 + ci) * 9 + t]);
    } else if (i < 55296 + 73728) {
        const int j = i - 55296;
        const int t = j / 8192, r = j % 8192, ko = r >> 6, ci = r & 63;
        wt1[j] = f2bits(W1[(ko * 64 + ci) * 9 + t]);
    }
}

// ---- x (64,32,64,64) f32 NCHW -> xT (64,64,64,32) bf16 NHWC ---------------
__global__ void transpose_kernel(const float* __restrict__ x, u16* __restrict__ xT) {
    const int img = blockIdx.x >> 6, h = blockIdx.x & 63;
    const int gq = threadIdx.x & 3, w = threadIdx.x >> 2;
    short8 o;
#pragma unroll
    for (int k = 0; k < 8; ++k)
        o[k] = (short)f2bits(x[((size_t)img * 32 + gq * 8 + k) * 4096 + h * 64 + w]);
    ((short8*)xT)[((size_t)(img * 64 + h) * 64 + w) * 4 + gq] = o;
}

// ---- fused layer 0: conv3x3(32->192) + minGRU scan + residual -------------
// X = xT (64,64,64,32) bf16 NHWC. wt [9][192][32] bf16; bias = b0 (128) f32.
// x1out (64,64,64,64) bf16 NHWC; hlast (4,64,64,64) f32 NCHW.
// Block = (b, 2-row strip, 32-col half): grid 4*32*2 = 256, 4 waves.
// Wave wv owns ko-groups {wv: gate, wv+4: hidden, wv+8: residual}: each
// thread's acc holds matched (gate,hidden,res) triples per pixel -> GRU is
// pure per-thread VALU. h persistent in regs across all 16 timesteps.
// Weights (27 granules = 108 VGPR) hoisted once per block.
__global__ __launch_bounds__(256, 1)
void fused_layer0_kernel(const u16* __restrict__ X, const u16* __restrict__ wt,
                         const float* __restrict__ bias,
                         u16* __restrict__ x1out, float* __restrict__ hlast) {
    __shared__ short8 lds[4 * 34 * 4];   // 8704 B

    const int tid = threadIdx.x;
    const int l   = tid & 63;
    const int wv  = tid >> 6;
    const int c16 = l & 15;
    const int q16 = l >> 4;

    const int bid = blockIdx.x;
    const int b   = bid >> 6;
    const int h0  = ((bid >> 1) & 31) * 2;
    const int w0  = (bid & 1) * 32;

    // ---- weights: 27 granules hoisted (9 taps x 3 groups) ----
    const short8* wtv = (const short8*)wt;
    short8 af[9][3];
#pragma unroll
    for (int t = 0; t < 9; ++t)
#pragma unroll
        for (int g = 0; g < 3; ++g)
            af[t][g] = wtv[(size_t)(t * 192 + (wv + g * 4) * 16 + c16) * 4 + q16];

    const floatx4 biasg = *(const floatx4*)(bias + wv * 16 + q16 * 4);
    const floatx4 biash = *(const floatx4*)(bias + 64 + wv * 16 + q16 * 4);

    // ---- staging geometry: 544 granules = 4r x 34c x 4q ----
    int ldsoff[3], goff[3];
    bool gval[3];
#pragma unroll
    for (int k = 0; k < 3; ++k) {
        const int idx = tid + k * 256;
        const int row = (idx >= 408) ? 3 : (idx >= 272) ? 2 : (idx >= 136) ? 1 : 0;
        const int rem = idx - row * 136;
        const int colrel = rem >> 2, q = rem & 3;
        const int hh = h0 - 1 + row;
        const int gc = w0 - 1 + colrel;
        ldsoff[k] = (row * 34 + colrel) * 4 + ((q + colrel) & 3);
        gval[k]   = (idx < 544) && ((unsigned)hh < 64u) && ((unsigned)gc < 64u);
        goff[k]   = (hh * 64 + gc) * 4 + q;
    }
    const bool k2 = (tid < 32);   // idx 512..543

    float hs[4][4];
#pragma unroll
    for (int m = 0; m < 4; ++m)
#pragma unroll
        for (int r = 0; r < 4; ++r) hs[m][r] = 0.5f;

    const short8* Xg = (const short8*)X;
    const short8 z8 = {0, 0, 0, 0, 0, 0, 0, 0};
    shortx4* x1v = (shortx4*)x1out;

    // prologue: load s=0 into regs
    short8 v0, v1, v2;
    {
        const short8* base = Xg + (size_t)(b * 16) * 16384;
        v0 = gval[0] ? base[goff[0]] : z8;
        v1 = gval[1] ? base[goff[1]] : z8;
        v2 = gval[2] ? base[goff[2]] : z8;
    }

    for (int s = 0; s < SS; ++s) {
        // write staged tile (invalid slots carry zeros -> halo stays zero)
        lds[ldsoff[0]] = v0;
        lds[ldsoff[1]] = v1;
        if (k2) lds[ldsoff[2]] = v2;
        __syncthreads();

        // prefetch next timestep while computing this one
        if (s + 1 < SS) {
            const short8* base = Xg + (size_t)(b * 16 + s + 1) * 16384;
            v0 = gval[0] ? base[goff[0]] : z8;
            v1 = gval[1] ? base[goff[1]] : z8;
            v2 = gval[2] ? base[goff[2]] : z8;
        }

        // conv: acc[0]=gate, acc[1]=hidden, acc[2]=residual; m = px-tile
        floatx4 acc[3][4];
#pragma unroll
        for (int m = 0; m < 4; ++m) {
            acc[0][m] = biasg; acc[1][m] = biash;
            acc[2][m] = floatx4{0.0f, 0.0f, 0.0f, 0.0f};
        }
#pragma unroll
        for (int t = 0; t < 9; ++t) {
            const int dy = t / 3, dx = t - dy * 3;
#pragma unroll
            for (int m = 0; m < 4; ++m) {
                const int row = (m >> 1) + dy;
                const int lc  = (m & 1) * 16 + c16 + dx;
                const short8 bf = lds[(row * 34 + lc) * 4 + ((q16 + lc) & 3)];
#pragma unroll
                for (int g = 0; g < 3; ++g)
                    acc[g][m] = __builtin_amdgcn_mfma_f32_16x16x32_bf16(
                        af[t][g], bf, acc[g][m], 0, 0, 0);
            }
        }

        // GRU update + residual + bf16 NHWC store of x1
#pragma unroll
        for (int m = 0; m < 4; ++m) {
            shortx4 ov;
#pragma unroll
            for (int r = 0; r < 4; ++r) {
                const float g   = acc[0][m][r];
                const float hid = acc[1][m][r];
                const float zz  = 1.0f / (1.0f + __expf(-g));
                const float gg  = (hid >= 0.0f) ? (hid + 0.5f)
                                                : (1.0f / (1.0f + __expf(-hid)));
                hs[m][r] = hs[m][r] + zz * (gg - hs[m][r]);
                ov[r] = (short)f2bits(hs[m][r] + acc[2][m][r]);
            }
            const size_t px = ((size_t)(b * 16 + s) * 64 + (h0 + (m >> 1))) * 64
                              + w0 + (m & 1) * 16 + c16;
            x1v[px * 16 + wv * 4 + q16] = ov;
        }
        __syncthreads();   // all waves done reading lds before next ds_write
    }

    // hlast (4,64,64,64) f32 NCHW
    float* hp = hlast + ((size_t)(b * 64) + (wv * 16 + q16 * 4)) * 4096
                      + h0 * 64 + w0 + c16;
#pragma unroll
    for (int m = 0; m < 4; ++m)
#pragma unroll
        for (int r = 0; r < 4; ++r)
            hp[(size_t)r * 4096 + (m >> 1) * 64 + (m & 1) * 16] = hs[m][r];
}

// ---- fused layer 1: conv3x3(64->128) + minGRU scan + residual -------------
// (verified 65us in round 6 — unchanged)
// X = x1 (64,64,64,64) bf16 NHWC. wt [9][128][64] bf16; bias (128) f32.
// out (4,16,64,64,64) f32 NCHW; hlast (4,64,64,64) f32 NCHW.
__global__ __launch_bounds__(256, 1)
void fused_layer1_kernel(const u16* __restrict__ X, const u16* __restrict__ wt,
                         const float* __restrict__ bias,
                         float* __restrict__ out, float* __restrict__ hlast) {
    __shared__ short8 lds[4 * 34 * 8];   // 17408 B

    const int tid = threadIdx.x;
    const int l   = tid & 63;
    const int wv  = tid >> 6;
    const int c16 = l & 15;
    const int q16 = l >> 4;

    const int bid = blockIdx.x;
    const int b   = bid >> 6;
    const int h0  = ((bid >> 1) & 31) * 2;
    const int w0  = (bid & 1) * 32;

    // ---- weights: all 36 granules hoisted (static across timesteps) ----
    const short8* wtv = (const short8*)wt;
    short8 af[2][9][2];
#pragma unroll
    for (int ch = 0; ch < 2; ++ch)
#pragma unroll
        for (int t = 0; t < 9; ++t)
#pragma unroll
            for (int g = 0; g < 2; ++g)
                af[ch][t][g] =
                    wtv[(size_t)(t * 128 + (wv + g * 4) * 16 + c16) * 8 + ch * 4 + q16];

    const floatx4 biasg = *(const floatx4*)(bias + wv * 16 + q16 * 4);
    const floatx4 biash = *(const floatx4*)(bias + 64 + wv * 16 + q16 * 4);

    // ---- staging geometry (static per thread): 1088 granules = 4r x 34c x 8q
    int ldsoff[5], goff[5];
    bool gval[5];
#pragma unroll
    for (int k = 0; k < 5; ++k) {
        const int idx = tid + k * 256;
        const int row = (idx >= 816) ? 3 : (idx >= 544) ? 2 : (idx >= 272) ? 1 : 0;
        const int rem = idx - row * 272;
        const int colrel = rem >> 3, q = rem & 7;
        const int hh = h0 - 1 + row;
        const int gc = w0 - 1 + colrel;
        ldsoff[k] = (row * 34 + colrel) * 8 + ((q + colrel) & 7);
        gval[k]   = (idx < 1088) && ((unsigned)hh < 64u) && ((unsigned)gc < 64u);
        goff[k]   = (hh * 64 + gc) * 8 + q;
    }
    const bool k4 = (tid < 64);   // k=4 slot exists only for idx<1088

    float hs[4][4];
#pragma unroll
    for (int m = 0; m < 4; ++m)
#pragma unroll
        for (int r = 0; r < 4; ++r) hs[m][r] = 0.5f;

    // out base for this thread: ch c=wv*16+q16*4, px (h0+(m>>1), w0+(m&1)*16+c16)
    float* op = out + ((size_t)(b * 16) * 64 + (wv * 16 + q16 * 4)) * 4096
                    + h0 * 64 + w0 + c16;

    const short8* Xg = (const short8*)X;
    const short8 z8 = {0, 0, 0, 0, 0, 0, 0, 0};

    // prologue: load s=0 into regs
    short8 v0, v1, v2, v3, v4;
    {
        const short8* base = Xg + (size_t)(b * 16) * 32768;
        v0 = gval[0] ? base[goff[0]] : z8;
        v1 = gval[1] ? base[goff[1]] : z8;
        v2 = gval[2] ? base[goff[2]] : z8;
        v3 = gval[3] ? base[goff[3]] : z8;
        v4 = gval[4] ? base[goff[4]] : z8;
    }

    for (int s = 0; s < SS; ++s) {
        // write staged tile (invalid slots carry zeros -> halo stays zero)
        lds[ldsoff[0]] = v0;
        lds[ldsoff[1]] = v1;
        lds[ldsoff[2]] = v2;
        lds[ldsoff[3]] = v3;
        if (k4) lds[ldsoff[4]] = v4;
        __syncthreads();

        // prefetch next timestep while computing this one
        if (s + 1 < SS) {
            const short8* base = Xg + (size_t)(b * 16 + s + 1) * 32768;
            v0 = gval[0] ? base[goff[0]] : z8;
            v1 = gval[1] ? base[goff[1]] : z8;
            v2 = gval[2] ? base[goff[2]] : z8;
            v3 = gval[3] ? base[goff[3]] : z8;
            v4 = gval[4] ? base[goff[4]] : z8;
        }

        // conv: acc[0]=gate tiles, acc[1]=hidden tiles, m = px-tile
        floatx4 acc[2][4];
#pragma unroll
        for (int m = 0; m < 4; ++m) { acc[0][m] = biasg; acc[1][m] = biash; }
#pragma unroll
        for (int ch = 0; ch < 2; ++ch)
#pragma unroll
            for (int t = 0; t < 9; ++t) {
                const int dy = t / 3, dx = t - dy * 3;
#pragma unroll
                for (int m = 0; m < 4; ++m) {
                    const int row = (m >> 1) + dy;
                    const int lc  = (m & 1) * 16 + c16 + dx;
                    const short8 bf =
                        lds[(row * 34 + lc) * 8 + ((ch * 4 + q16 + lc) & 7)];
                    acc[0][m] = __builtin_amdgcn_mfma_f32_16x16x32_bf16(
                        af[ch][t][0], bf, acc[0][m], 0, 0, 0);
                    acc[1][m] = __builtin_amdgcn_mfma_f32_16x16x32_bf16(
                        af[ch][t][1], bf, acc[1][m], 0, 0, 0);
                }
            }

        // GRU update + residual + direct NCHW f32 store
        float* ops = op + (size_t)s * 262144;   // 64*4096 floats per timestep
        const int qres = wv * 2 + (q16 >> 1);
#pragma unroll
        for (int m = 0; m < 4; ++m) {
            const int rowc = 1 + (m >> 1);
            const int lcc  = 1 + (m & 1) * 16 + c16;
            const shortx4 rr = *(const shortx4*)(
                (const short*)&lds[(rowc * 34 + lcc) * 8 + ((qres + lcc) & 7)]
                + (q16 & 1) * 4);
#pragma unroll
            for (int r = 0; r < 4; ++r) {
                const float g   = acc[0][m][r];
                const float hid = acc[1][m][r];
                const float zz  = 1.0f / (1.0f + __expf(-g));
                const float gg  = (hid >= 0.0f) ? (hid + 0.5f)
                                                : (1.0f / (1.0f + __expf(-hid)));
                hs[m][r] = hs[m][r] + zz * (gg - hs[m][r]);
                const float o = hs[m][r] + bits2f((u16)rr[r]);
                ops[(size_t)r * 4096 + (m >> 1) * 64 + (m & 1) * 16] = o;
            }
        }
        __syncthreads();   // all waves done reading lds before next ds_write
    }

    // hlast (4,64,64,64) f32 NCHW
    float* hp = hlast + ((size_t)(b * 64) + (wv * 16 + q16 * 4)) * 4096
                      + h0 * 64 + w0 + c16;
#pragma unroll
    for (int m = 0; m < 4; ++m)
#pragma unroll
        for (int r = 0; r < 4; ++r)
            hp[(size_t)r * 4096 + (m >> 1) * 64 + (m & 1) * 16] = hs[m][r];
}

extern "C" void kernel_launch(void* const* d_in, const int* in_sizes, int n_in,
                              void* d_out, int out_size, void* d_ws, size_t ws_size,
                              hipStream_t stream) {
    const float* x  = (const float*)d_in[0];   // (4,16,32,64,64)
    const float* W0 = (const float*)d_in[1];   // (128,32,3,3)
    const float* b0 = (const float*)d_in[2];   // (128,)
    const float* R0 = (const float*)d_in[3];   // (64,32,3,3)
    const float* W1 = (const float*)d_in[4];   // (128,64,3,3)
    const float* b1 = (const float*)d_in[5];   // (128,)

    float* out = (float*)d_out;                 // (4,16,64,64,64) NCHW f32
    float* h0o = out + (size_t)16777216;
    float* h1o = h0o + (size_t)1048576;

    char* ws = (char*)d_ws;
    u16*   wt0f = (u16*)ws;                             // 110,592 B
    u16*   wt1  = (u16*)(ws + 110592);                  // 147,456 B -> ends 258,048
    u16*   xT   = (u16*)(ws + (size_t)(1  << 20));      // 16 MiB (NHWC bf16 input)
    u16*   x1   = (u16*)(ws + (size_t)(18 << 20));      // 32 MiB -> ends 50 MiB

    prep_kernel<<<504, 256, 0, stream>>>(W0, R0, W1, wt0f, wt1);
    transpose_kernel<<<4096, 256, 0, stream>>>(x, xT);

    // Layer 0: fused conv(32->192: gate/hidden/res) + GRU scan -> x1, h0o
    fused_layer0_kernel<<<256, 256, 0, stream>>>(xT, wt0f, b0, x1, h0o);

    // Layer 1: fused conv(64->128) + GRU scan + identity residual -> out, h1o
    fused_layer1_kernel<<<256, 256, 0, stream>>>(x1, wt1, b1, out, h1o);
}

// Round 8
// 183.059 us; speedup vs baseline: 2.3523x; 1.1276x over previous
//
#include <hip/hip_runtime.h>

typedef short short8  __attribute__((ext_vector_type(8)));
typedef short shortx4 __attribute__((ext_vector_type(4)));
typedef float floatx4 __attribute__((ext_vector_type(4)));
typedef unsigned short u16;

static __device__ __forceinline__ float bits2f(u16 s) {
    return __builtin_bit_cast(float, (unsigned)s << 16);
}
static __device__ __forceinline__ u16 f2bits(float f) {
    return __builtin_bit_cast(u16, (__bf16)f);   // RNE
}

#define SS 16

// ---- weight prepack ------------------------------------------------------
// wt0f [9][192][32] bf16 : ko<128 from W0 (gate 0-63, hidden 64-127),
//                          ko>=128 from R0 (residual).
// wt1  [9][128][64] bf16
__global__ void prep_kernel(const float* W0, const float* R0, const float* W1,
                            u16* wt0f, u16* wt1) {
    const int i = blockIdx.x * 256 + threadIdx.x;
    if (i < 55296) {
        const int t = i / 6144, r = i % 6144, ko = r >> 5, ci = r & 31;
        wt0f[i] = f2bits(ko < 128 ? W0[(ko * 32 + ci) * 9 + t]
                                  : R0[((ko - 128) * 32 + ci) * 9 + t]);
    } else if (i < 55296 + 73728) {
        const int j = i - 55296;
        const int t = j / 8192, r = j % 8192, ko = r >> 6, ci = r & 63;
        wt1[j] = f2bits(W1[(ko * 64 + ci) * 9 + t]);
    }
}

// ---- x (64,32,64,64) f32 NCHW -> xT (64,64,64,32) bf16 NHWC ---------------
__global__ void transpose_kernel(const float* __restrict__ x, u16* __restrict__ xT) {
    const int img = blockIdx.x >> 6, h = blockIdx.x & 63;
    const int gq = threadIdx.x & 3, w = threadIdx.x >> 2;
    short8 o;
#pragma unroll
    for (int k = 0; k < 8; ++k)
        o[k] = (short)f2bits(x[((size_t)img * 32 + gq * 8 + k) * 4096 + h * 64 + w]);
    ((short8*)xT)[((size_t)(img * 64 + h) * 64 + w) * 4 + gq] = o;
}

// ---- fused layer 0: conv3x3(32->192) + minGRU scan + residual -------------
// X = xT (64,64,64,32) bf16 NHWC. wt [9][192][32] bf16; bias = b0 (128) f32.
// x1out (64,64,64,64) bf16 NHWC; hlast (4,64,64,64) f32 NCHW.
// Tile = 2 rows x 16 cols -> grid 4b*32strips*4colq = 512 = 2 blocks/CU
// (r7 was 256 = 1 block/CU: every sync stalled the whole CU; co-resident
// sibling now fills the bubbles). Wave wv owns ko-groups {wv,wv+4,wv+8} =
// (gate,hidden,res) triples per thread -> GRU is pure per-thread VALU.
__global__ __launch_bounds__(256, 2)
void fused_layer0_kernel(const u16* __restrict__ X, const u16* __restrict__ wt,
                         const float* __restrict__ bias,
                         u16* __restrict__ x1out, float* __restrict__ hlast) {
    __shared__ short8 lds[4 * 18 * 4];   // 4608 B

    const int tid = threadIdx.x;
    const int l   = tid & 63;
    const int wv  = tid >> 6;
    const int c16 = l & 15;
    const int q16 = l >> 4;

    const int bid = blockIdx.x;
    const int b   = bid >> 7;               // 128 blocks per batch image-set
    const int h0  = ((bid >> 2) & 31) * 2;
    const int w0  = (bid & 3) * 16;

    // ---- weights: 27 granules hoisted (9 taps x 3 groups) ----
    const short8* wtv = (const short8*)wt;
    short8 af[9][3];
#pragma unroll
    for (int t = 0; t < 9; ++t)
#pragma unroll
        for (int g = 0; g < 3; ++g)
            af[t][g] = wtv[(size_t)(t * 192 + (wv + g * 4) * 16 + c16) * 4 + q16];

    const floatx4 biasg = *(const floatx4*)(bias + wv * 16 + q16 * 4);
    const floatx4 biash = *(const floatx4*)(bias + 64 + wv * 16 + q16 * 4);

    // ---- staging geometry: 288 granules = 4r x 18c x 4q ----
    int ldsoff[2], goff[2];
    bool gval[2];
#pragma unroll
    for (int k = 0; k < 2; ++k) {
        const int idx = tid + k * 256;
        const int row = (idx >= 216) ? 3 : (idx >= 144) ? 2 : (idx >= 72) ? 1 : 0;
        const int rem = idx - row * 72;
        const int colrel = rem >> 2, q = rem & 3;
        const int hh = h0 - 1 + row;
        const int gc = w0 - 1 + colrel;
        ldsoff[k] = (row * 18 + colrel) * 4 + ((q + colrel) & 3);
        gval[k]   = (idx < 288) && ((unsigned)hh < 64u) && ((unsigned)gc < 64u);
        goff[k]   = (hh * 64 + gc) * 4 + q;
    }
    const bool k1 = (tid < 32);   // idx 256..287

    float hs[2][4];
#pragma unroll
    for (int m = 0; m < 2; ++m)
#pragma unroll
        for (int r = 0; r < 4; ++r) hs[m][r] = 0.5f;

    const short8* Xg = (const short8*)X;
    const short8 z8 = {0, 0, 0, 0, 0, 0, 0, 0};
    shortx4* x1v = (shortx4*)x1out;

    // prologue: load s=0 into regs
    short8 v0, v1;
    {
        const short8* base = Xg + (size_t)(b * 16) * 16384;
        v0 = gval[0] ? base[goff[0]] : z8;
        v1 = gval[1] ? base[goff[1]] : z8;
    }

    for (int s = 0; s < SS; ++s) {
        lds[ldsoff[0]] = v0;
        if (k1) lds[ldsoff[1]] = v1;
        __syncthreads();

        // prefetch next timestep while computing this one
        if (s + 1 < SS) {
            const short8* base = Xg + (size_t)(b * 16 + s + 1) * 16384;
            v0 = gval[0] ? base[goff[0]] : z8;
            v1 = gval[1] ? base[goff[1]] : z8;
        }

        // conv: acc[0]=gate, acc[1]=hidden, acc[2]=residual; m = out row
        floatx4 acc[3][2];
#pragma unroll
        for (int m = 0; m < 2; ++m) {
            acc[0][m] = biasg; acc[1][m] = biash;
            acc[2][m] = floatx4{0.0f, 0.0f, 0.0f, 0.0f};
        }
#pragma unroll
        for (int t = 0; t < 9; ++t) {
            const int dy = t / 3, dx = t - dy * 3;
#pragma unroll
            for (int m = 0; m < 2; ++m) {
                const int row = m + dy;
                const int lc  = c16 + dx;
                const short8 bf = lds[(row * 18 + lc) * 4 + ((q16 + lc) & 3)];
#pragma unroll
                for (int g = 0; g < 3; ++g)
                    acc[g][m] = __builtin_amdgcn_mfma_f32_16x16x32_bf16(
                        af[t][g], bf, acc[g][m], 0, 0, 0);
            }
        }

        // GRU update + residual + bf16 NHWC store of x1
#pragma unroll
        for (int m = 0; m < 2; ++m) {
            shortx4 ov;
#pragma unroll
            for (int r = 0; r < 4; ++r) {
                const float g   = acc[0][m][r];
                const float hid = acc[1][m][r];
                const float zz  = 1.0f / (1.0f + __expf(-g));
                const float gg  = (hid >= 0.0f) ? (hid + 0.5f)
                                                : (1.0f / (1.0f + __expf(-hid)));
                hs[m][r] = hs[m][r] + zz * (gg - hs[m][r]);
                ov[r] = (short)f2bits(hs[m][r] + acc[2][m][r]);
            }
            const size_t px = ((size_t)(b * 16 + s) * 64 + (h0 + m)) * 64
                              + w0 + c16;
            x1v[px * 16 + wv * 4 + q16] = ov;
        }
        __syncthreads();   // all waves done reading lds before next ds_write
    }

    // hlast (4,64,64,64) f32 NCHW
    float* hp = hlast + ((size_t)(b * 64) + (wv * 16 + q16 * 4)) * 4096
                      + h0 * 64 + w0 + c16;
#pragma unroll
    for (int m = 0; m < 2; ++m)
#pragma unroll
        for (int r = 0; r < 4; ++r)
            hp[(size_t)r * 4096 + m * 64] = hs[m][r];
}

// ---- fused layer 1: conv3x3(64->128) + minGRU scan + residual -------------
// X = x1 (64,64,64,64) bf16 NHWC. wt [9][128][64] bf16; bias (128) f32.
// out (4,16,64,64,64) f32 NCHW; hlast (4,64,64,64) f32 NCHW.
// Tile = 2 rows x 16 cols, grid 512 = 2 blocks/CU (see layer-0 note).
// Wave wv owns ko-tiles {wv: gate, wv+4: hidden} -> matched pairs per thread.
__global__ __launch_bounds__(256, 2)
void fused_layer1_kernel(const u16* __restrict__ X, const u16* __restrict__ wt,
                         const float* __restrict__ bias,
                         float* __restrict__ out, float* __restrict__ hlast) {
    __shared__ short8 lds[4 * 18 * 8];   // 9216 B

    const int tid = threadIdx.x;
    const int l   = tid & 63;
    const int wv  = tid >> 6;
    const int c16 = l & 15;
    const int q16 = l >> 4;

    const int bid = blockIdx.x;
    const int b   = bid >> 7;
    const int h0  = ((bid >> 2) & 31) * 2;
    const int w0  = (bid & 3) * 16;

    // ---- weights: 36 granules hoisted (2 ch-halves x 9 taps x 2 groups) ----
    const short8* wtv = (const short8*)wt;
    short8 af[2][9][2];
#pragma unroll
    for (int ch = 0; ch < 2; ++ch)
#pragma unroll
        for (int t = 0; t < 9; ++t)
#pragma unroll
            for (int g = 0; g < 2; ++g)
                af[ch][t][g] =
                    wtv[(size_t)(t * 128 + (wv + g * 4) * 16 + c16) * 8 + ch * 4 + q16];

    const floatx4 biasg = *(const floatx4*)(bias + wv * 16 + q16 * 4);
    const floatx4 biash = *(const floatx4*)(bias + 64 + wv * 16 + q16 * 4);

    // ---- staging geometry: 576 granules = 4r x 18c x 8q ----
    int ldsoff[3], goff[3];
    bool gval[3];
#pragma unroll
    for (int k = 0; k < 3; ++k) {
        const int idx = tid + k * 256;
        const int row = (idx >= 432) ? 3 : (idx >= 288) ? 2 : (idx >= 144) ? 1 : 0;
        const int rem = idx - row * 144;
        const int colrel = rem >> 3, q = rem & 7;
        const int hh = h0 - 1 + row;
        const int gc = w0 - 1 + colrel;
        ldsoff[k] = (row * 18 + colrel) * 8 + ((q + colrel) & 7);
        gval[k]   = (idx < 576) && ((unsigned)hh < 64u) && ((unsigned)gc < 64u);
        goff[k]   = (hh * 64 + gc) * 8 + q;
    }
    const bool k2 = (tid < 64);   // idx 512..575

    float hs[2][4];
#pragma unroll
    for (int m = 0; m < 2; ++m)
#pragma unroll
        for (int r = 0; r < 4; ++r) hs[m][r] = 0.5f;

    // out base: ch c=wv*16+q16*4, px (h0+m, w0+c16)
    float* op = out + ((size_t)(b * 16) * 64 + (wv * 16 + q16 * 4)) * 4096
                    + h0 * 64 + w0 + c16;

    const short8* Xg = (const short8*)X;
    const short8 z8 = {0, 0, 0, 0, 0, 0, 0, 0};

    // prologue: load s=0 into regs
    short8 v0, v1, v2;
    {
        const short8* base = Xg + (size_t)(b * 16) * 32768;
        v0 = gval[0] ? base[goff[0]] : z8;
        v1 = gval[1] ? base[goff[1]] : z8;
        v2 = gval[2] ? base[goff[2]] : z8;
    }

    for (int s = 0; s < SS; ++s) {
        lds[ldsoff[0]] = v0;
        lds[ldsoff[1]] = v1;
        if (k2) lds[ldsoff[2]] = v2;
        __syncthreads();

        // prefetch next timestep while computing this one
        if (s + 1 < SS) {
            const short8* base = Xg + (size_t)(b * 16 + s + 1) * 32768;
            v0 = gval[0] ? base[goff[0]] : z8;
            v1 = gval[1] ? base[goff[1]] : z8;
            v2 = gval[2] ? base[goff[2]] : z8;
        }

        // conv: acc[0]=gate, acc[1]=hidden; m = out row
        floatx4 acc[2][2];
#pragma unroll
        for (int m = 0; m < 2; ++m) { acc[0][m] = biasg; acc[1][m] = biash; }
#pragma unroll
        for (int ch = 0; ch < 2; ++ch)
#pragma unroll
            for (int t = 0; t < 9; ++t) {
                const int dy = t / 3, dx = t - dy * 3;
#pragma unroll
                for (int m = 0; m < 2; ++m) {
                    const int row = m + dy;
                    const int lc  = c16 + dx;
                    const short8 bf =
                        lds[(row * 18 + lc) * 8 + ((ch * 4 + q16 + lc) & 7)];
                    acc[0][m] = __builtin_amdgcn_mfma_f32_16x16x32_bf16(
                        af[ch][t][0], bf, acc[0][m], 0, 0, 0);
                    acc[1][m] = __builtin_amdgcn_mfma_f32_16x16x32_bf16(
                        af[ch][t][1], bf, acc[1][m], 0, 0, 0);
                }
            }

        // GRU update + residual (from staged LDS) + direct NCHW f32 store
        float* ops = op + (size_t)s * 262144;   // 64*4096 floats per timestep
        const int qres = wv * 2 + (q16 >> 1);
#pragma unroll
        for (int m = 0; m < 2; ++m) {
            const int rowc = 1 + m;
            const int lcc  = 1 + c16;
            const shortx4 rr = *(const shortx4*)(
                (const short*)&lds[(rowc * 18 + lcc) * 8 + ((qres + lcc) & 7)]
                + (q16 & 1) * 4);
#pragma unroll
            for (int r = 0; r < 4; ++r) {
                const float g   = acc[0][m][r];
                const float hid = acc[1][m][r];
                const float zz  = 1.0f / (1.0f + __expf(-g));
                const float gg  = (hid >= 0.0f) ? (hid + 0.5f)
                                                : (1.0f / (1.0f + __expf(-hid)));
                hs[m][r] = hs[m][r] + zz * (gg - hs[m][r]);
                const float o = hs[m][r] + bits2f((u16)rr[r]);
                ops[(size_t)r * 4096 + m * 64] = o;
            }
        }
        __syncthreads();   // all waves done reading lds before next ds_write
    }

    // hlast (4,64,64,64) f32 NCHW
    float* hp = hlast + ((size_t)(b * 64) + (wv * 16 + q16 * 4)) * 4096
                      + h0 * 64 + w0 + c16;
#pragma unroll
    for (int m = 0; m < 2; ++m)
#pragma unroll
        for (int r = 0; r < 4; ++r)
            hp[(size_t)r * 4096 + m * 64] = hs[m][r];
}

extern "C" void kernel_launch(void* const* d_in, const int* in_sizes, int n_in,
                              void* d_out, int out_size, void* d_ws, size_t ws_size,
                              hipStream_t stream) {
    const float* x  = (const float*)d_in[0];   // (4,16,32,64,64)
    const float* W0 = (const float*)d_in[1];   // (128,32,3,3)
    const float* b0 = (const float*)d_in[2];   // (128,)
    const float* R0 = (const float*)d_in[3];   // (64,32,3,3)
    const float* W1 = (const float*)d_in[4];   // (128,64,3,3)
    const float* b1 = (const float*)d_in[5];   // (128,)

    float* out = (float*)d_out;                 // (4,16,64,64,64) NCHW f32
    float* h0o = out + (size_t)16777216;
    float* h1o = h0o + (size_t)1048576;

    char* ws = (char*)d_ws;
    u16*   wt0f = (u16*)ws;                             // 110,592 B
    u16*   wt1  = (u16*)(ws + 110592);                  // 147,456 B -> ends 258,048
    u16*   xT   = (u16*)(ws + (size_t)(1  << 20));      // 16 MiB (NHWC bf16 input)
    u16*   x1   = (u16*)(ws + (size_t)(18 << 20));      // 32 MiB -> ends 50 MiB

    prep_kernel<<<504, 256, 0, stream>>>(W0, R0, W1, wt0f, wt1);
    transpose_kernel<<<4096, 256, 0, stream>>>(x, xT);

    // Layer 0: fused conv(32->192: gate/hidden/res) + GRU scan -> x1, h0o
    fused_layer0_kernel<<<512, 256, 0, stream>>>(xT, wt0f, b0, x1, h0o);

    // Layer 1: fused conv(64->128) + GRU scan + identity residual -> out, h1o
    fused_layer1_kernel<<<512, 256, 0, stream>>>(x1, wt1, b1, out, h1o);
}